// Round 23
// baseline (5709.503 us; speedup 1.0000x reference)
//
#include <hip/hip_runtime.h>

// LSTM: B=64, S=512, I=H=O=1024.  bf16 MFMA, fp32 accum.
// R23 = R22 with SPECULATIVE h-load issue: all 32 h loads are issued BEFORE
// the flag polls (poison net makes this safe), so the h-load LLC round trip
// overlaps the flag-poll round trip instead of following it. Polls' in-order
// vmcnt drains are free (data issued first). Validate per group (CHKMAX,
// rare 8-load retry) then consume.
//  - Flags posted WITHOUT store drain; 16-slot poisoned h ring; delayed
//    own-rows re-poison (R18-proven); free-running per-wave chains.
//  - Factories: per-wave, <=4 ahead, cached xT loads, xpart ring + xflg.

typedef __bf16 bfv8 __attribute__((ext_vector_type(8)));
typedef float f32x4 __attribute__((ext_vector_type(4)));
typedef unsigned int u32v4 __attribute__((ext_vector_type(4)));

__device__ __forceinline__ unsigned short f2bf(float x) {
    union { float f; unsigned int u; } v; v.f = x;
    unsigned int r = (v.u + 0x7FFFu + ((v.u >> 16) & 1u)) >> 16;
    return (unsigned short)r;
}
__device__ __forceinline__ float bf2f(unsigned short s) {
    union { unsigned int u; float f; } v; v.u = ((unsigned int)s) << 16;
    return v.f;
}

struct SrcPtrs { const float* p[9]; };

// Device-scope (LLC-coherent) issue — exchange traffic.
#define ISSUE8(A, P, O0, O1, O2, O3, O4, O5, O6, O7)                         \
    asm volatile(                                                            \
        "global_load_dwordx4 %0, %8, off offset:" O0 " sc1\n\t"              \
        "global_load_dwordx4 %1, %8, off offset:" O1 " sc1\n\t"              \
        "global_load_dwordx4 %2, %8, off offset:" O2 " sc1\n\t"              \
        "global_load_dwordx4 %3, %8, off offset:" O3 " sc1\n\t"              \
        "global_load_dwordx4 %4, %8, off offset:" O4 " sc1\n\t"              \
        "global_load_dwordx4 %5, %8, off offset:" O5 " sc1\n\t"              \
        "global_load_dwordx4 %6, %8, off offset:" O6 " sc1\n\t"              \
        "global_load_dwordx4 %7, %8, off offset:" O7 " sc1"                  \
        : "=&v"(A[0]), "=&v"(A[1]), "=&v"(A[2]), "=&v"(A[3]),                \
          "=&v"(A[4]), "=&v"(A[5]), "=&v"(A[6]), "=&v"(A[7])                 \
        : "v"(P)                                                             \
        : "memory")

// Plain cached — factory xT loads (read-only, L2-shared per XCD).
#define ISSUE8C(A, P, O0, O1, O2, O3, O4, O5, O6, O7)                        \
    asm volatile(                                                            \
        "global_load_dwordx4 %0, %8, off offset:" O0 "\n\t"                  \
        "global_load_dwordx4 %1, %8, off offset:" O1 "\n\t"                  \
        "global_load_dwordx4 %2, %8, off offset:" O2 "\n\t"                  \
        "global_load_dwordx4 %3, %8, off offset:" O3 "\n\t"                  \
        "global_load_dwordx4 %4, %8, off offset:" O4 "\n\t"                  \
        "global_load_dwordx4 %5, %8, off offset:" O5 "\n\t"                  \
        "global_load_dwordx4 %6, %8, off offset:" O6 "\n\t"                  \
        "global_load_dwordx4 %7, %8, off offset:" O7                         \
        : "=&v"(A[0]), "=&v"(A[1]), "=&v"(A[2]), "=&v"(A[3]),                \
          "=&v"(A[4]), "=&v"(A[5]), "=&v"(A[6]), "=&v"(A[7])                 \
        : "v"(P)                                                             \
        : "memory")

#define WAIT8(N, A)                                                          \
    do {                                                                     \
        asm volatile("s_waitcnt vmcnt(" N ")"                                \
                     : "+v"(A[0]), "+v"(A[1]), "+v"(A[2]), "+v"(A[3]),       \
                       "+v"(A[4]), "+v"(A[5]), "+v"(A[6]), "+v"(A[7])        \
                     :: "memory");                                           \
        __builtin_amdgcn_sched_barrier(0);                                   \
    } while (0)

// 8 k-steps x 2 N-tiles vs fragment-linear LDS panel: lane-stride-1.
#define CONSUME8(A, IT0)                                                     \
    _Pragma("unroll")                                                        \
    for (int j = 0; j < 8; ++j) {                                            \
        _Pragma("unroll")                                                    \
        for (int n = 0; n < 2; ++n) {                                        \
            const int off = (((((IT0) + j) << 1) | n) << 10) + (lane << 4);  \
            acc[n] = __builtin_amdgcn_mfma_f32_16x16x32_bf16(                \
                A[j], *(const bfv8*)(Lw + off), acc[n], 0, 0, 0);            \
        }                                                                    \
    }

#define CHKMAX(A)                                                            \
    _Pragma("unroll")                                                        \
    for (int j = 0; j < 8; ++j) {                                            \
        const u32v4 u = __builtin_bit_cast(u32v4, A[j]);                     \
        mh = mh > u.x ? mh : u.x;                                            \
        mh = mh > u.y ? mh : u.y;                                            \
        mh = mh > u.z ? mh : u.z;                                            \
        mh = mh > u.w ? mh : u.w;                                            \
    }

// Per-group validate: check A for poison; rare retry re-issues and drains.
#define VALIDATE(A, O0, O1, O2, O3, O4, O5, O6, O7)                          \
    do {                                                                     \
        unsigned mh = 0;                                                     \
        CHKMAX(A)                                                            \
        int guard = 0;                                                       \
        while (__any(mh == 0xFFFFFFFFu) && ++guard <= 65536) {               \
            ISSUE8(A, hp, O0, O1, O2, O3, O4, O5, O6, O7);                   \
            WAIT8("0", A);                                                   \
            mh = 0;                                                          \
            CHKMAX(A)                                                        \
        }                                                                    \
    } while (0)

// ---------------------------------------------------------------------------
__global__ __launch_bounds__(256) void pack_weights(SrcPtrs sp,
                                                    unsigned short* __restrict__ Whp,
                                                    unsigned short* __restrict__ Wip,
                                                    unsigned short* __restrict__ Wy) {
    __shared__ float tile[64][65];
    const int z = blockIdx.z;
    const float* __restrict__ src = sp.p[z];
    const int n0 = blockIdx.x * 64, k0 = blockIdx.y * 64;
    const int tc = threadIdx.x & 63, tq = threadIdx.x >> 6;

    #pragma unroll
    for (int r = 0; r < 16; ++r) {
        const int kk = tq * 16 + r;
        tile[kk][tc] = src[(size_t)(k0 + kk) * 1024 + n0 + tc];
    }
    __syncthreads();
    #pragma unroll
    for (int r = 0; r < 16; ++r) {
        const int nl = tq * 16 + r;
        const int n = n0 + nl;
        const int k = k0 + tc;
        const unsigned short v = f2bf(tile[tc][nl]);
        if (z < 8) {
            const int g = z & 3;
            const int blk = n >> 3;
            const int c = (g << 3) | (n & 7);
            const int lanef = (c & 15) | (((k >> 3) & 3) << 4);
            const size_t off = ((size_t)((((blk << 5) | (k >> 5)) << 1) | (c >> 4)) << 9)
                             + (lanef << 3) + (k & 7);
            (z < 4 ? Whp : Wip)[off] = v;
        } else {
            Wy[(size_t)n * 1024 + k] = v;
        }
    }
}

// ---------------------------------------------------------------------------
__global__ __launch_bounds__(256) void convert_x(const float* __restrict__ x,
                                                 unsigned short* __restrict__ xT) {
    const size_t gid = (size_t)blockIdx.x * 256 + threadIdx.x;
    const int i0 = (int)(gid & 255) * 4;
    const size_t row = gid >> 8;            // dst row = t*64 + b
    const int t = (int)(row >> 6), b = (int)(row & 63);
    const float4 v = *reinterpret_cast<const float4*>(x + (((size_t)b * 512 + t) << 10) + i0);
    ushort4 o;
    o.x = f2bf(v.x); o.y = f2bf(v.y); o.z = f2bf(v.z); o.w = f2bf(v.w);
    *reinterpret_cast<ushort4*>(xT + (row << 10) + i0) = o;
}

// ---------------------------------------------------------------------------
// R23 unified producer/consumer kernel. 256 blocks x 256 thr.
// ---------------------------------------------------------------------------
__global__ __launch_bounds__(256) void lstm_pc(const unsigned short* __restrict__ xT,
                                               const unsigned short* __restrict__ Whp,
                                               const unsigned short* __restrict__ Wip,
                                               unsigned short* __restrict__ hring,
                                               int* __restrict__ xflg,
                                               int* __restrict__ cflg,
                                               int* __restrict__ flg,
                                               unsigned short* __restrict__ ring) {
    __shared__ struct {
        __align__(16) unsigned char wp[65536];   // fragment-linear W panel
        __align__(16) unsigned char pad[32768];  // force 1 block/CU
        __align__(16) unsigned short hs[64][8];  // h store-coalescing tile
    } L;
    unsigned char* Lw = L.wp;

    const int tid = threadIdx.x;
    const int w = tid >> 6;           // 0..3
    const int lane = tid & 63;
    const int lr = lane & 15;
    const int kq = lane >> 4;
    const bool isFactory = (blockIdx.x >= 128);
    const int b = isFactory ? (blockIdx.x - 128) : blockIdx.x;   // pair id

    // ---- stage panel (W_h for consumers, W_i for factories) ----
    {
        const unsigned short* src = (isFactory ? Wip : Whp) + ((size_t)b << 15);
        #pragma unroll
        for (int s = 0; s < 16; ++s) {
            const int c = s * 256 + tid;          // 16B chunk 0..4095
            *(bfv8*)(L.wp + c * 16) = *(const bfv8*)(src + c * 8);
        }
    }
    __syncthreads();   // only block-wide barrier

    const int roff = ((w << 4) + lr) * 1024 + kq * 8;
    const int pw = (b << 2) + w;                      // pair-wave id 0..511

    if (isFactory) {
        // ===== x-factory: per-wave, <=4 ahead, CACHED xT loads =====
        for (int tt = 0; tt < 512; ++tt) {
            const int* cfp = cflg + pw * 32;
            while (__hip_atomic_load(cfp, __ATOMIC_RELAXED, __HIP_MEMORY_SCOPE_AGENT) < tt - 4)
                __builtin_amdgcn_s_sleep(2);

            const unsigned short* Axp = xT + ((size_t)tt << 16) + roff;
            f32x4 acc[2] = {};
            bfv8 A0[8], A1[8];
            ISSUE8C(A0, Axp, "0", "64", "128", "192", "256", "320", "384", "448");
            ISSUE8C(A1, Axp, "512", "576", "640", "704", "768", "832", "896", "960");
            WAIT8("8", A0);
            CONSUME8(A0, 0);
            ISSUE8C(A0, Axp, "1024", "1088", "1152", "1216", "1280", "1344", "1408", "1472");
            WAIT8("8", A1);
            CONSUME8(A1, 8);
            ISSUE8C(A1, Axp, "1536", "1600", "1664", "1728", "1792", "1856", "1920", "1984");
            WAIT8("8", A0);
            CONSUME8(A0, 16);
            WAIT8("0", A1);
            CONSUME8(A1, 24);

            unsigned short vv[8];
            #pragma unroll
            for (int n = 0; n < 2; ++n)
                #pragma unroll
                for (int r = 0; r < 4; ++r)
                    vv[n * 4 + r] = f2bf(acc[n][r]);
            unsigned short* rp = ring + (((size_t)(b << 2) + (tt & 3)) * 4 + w) * 512 + lane * 8;
            asm volatile("global_store_dwordx4 %0, %1, off sc1"
                         :: "v"(rp), "v"(*(const u32v4*)vv) : "memory");
            asm volatile("s_waitcnt vmcnt(0)" ::: "memory");   // xpart has no poison net
            if (lane == 0)
                asm volatile("global_store_dword %0, %1, off sc1"
                             :: "v"(xflg + pw * 32), "v"(tt + 1) : "memory");
        }
        return;
    }

    // ================= consumer: free-running per-wave chain =================
    float cst[4] = {0.f, 0.f, 0.f, 0.f};
    bfv8 A0[8], A1[8], A2[8], A3[8];
    const u32v4 PZ = {0xFFFFFFFFu, 0xFFFFFFFFu, 0xFFFFFFFFu, 0xFFFFFFFFu};

    for (int t = 0; t < 512; ++t) {
        const unsigned short* hp = hring + ((size_t)(t & 15) << 16) + roff;

        // xpart: poll partner factory wave's flag, then load own 16B chunk
        const int* xfp = xflg + pw * 32;
        while (__hip_atomic_load(xfp, __ATOMIC_RELAXED, __HIP_MEMORY_SCOPE_AGENT) < t + 1)
            __builtin_amdgcn_s_sleep(1);
        u32v4 xp;
        const unsigned short* rp = ring + (((size_t)(b << 2) + (t & 3)) * 4 + w) * 512 + lane * 8;
        asm volatile("global_load_dwordx4 %0, %1, off sc1"
                     : "=v"(xp) : "v"(rp) : "memory");

        // SPECULATIVE h issue: all 4 groups before any flag poll (poison-safe)
        ISSUE8(A0, hp, "0", "64", "128", "192", "256", "320", "384", "448");
        ISSUE8(A1, hp, "512", "576", "640", "704", "768", "832", "896", "960");
        ISSUE8(A2, hp, "1024", "1088", "1152", "1216", "1280", "1344", "1408", "1472");
        ISSUE8(A3, hp, "1536", "1600", "1664", "1728", "1792", "1856", "1920", "1984");

        // flag polls overlap the data flights (in-order drains are free)
        #define POLLG(G)                                                      \
            if (t > 0) {                                                      \
                const int* fp = flg + (((((G) << 5) + (lane & 31)) << 2) | w) * 32; \
                for (;;) {                                                    \
                    const int f = __hip_atomic_load(fp, __ATOMIC_RELAXED,     \
                                                    __HIP_MEMORY_SCOPE_AGENT);\
                    if (__all(f >= t)) break;                                 \
                    __builtin_amdgcn_s_sleep(1);                              \
                }                                                             \
            }
        POLLG(0) POLLG(1) POLLG(2) POLLG(3)
        #undef POLLG

        // validate + consume (everything drained by the polls' in-order waits)
        f32x4 acc[2] = {};
        WAIT8("0", A0);
        asm volatile("" : "+v"(xp));        // xp secured in regs
        VALIDATE(A0, "0", "64", "128", "192", "256", "320", "384", "448");
        CONSUME8(A0, 0);
        // release the xpart slot for the factory (xp secured above)
        if (lane == 0)
            asm volatile("global_store_dword %0, %1, off sc1"
                         :: "v"(cflg + pw * 32), "v"(t) : "memory");
        WAIT8("1", A1);                     // cflg store may be outstanding
        VALIDATE(A1, "512", "576", "640", "704", "768", "832", "896", "960");
        CONSUME8(A1, 8);
        WAIT8("1", A2);
        VALIDATE(A2, "1024", "1088", "1152", "1216", "1280", "1344", "1408", "1472");
        CONSUME8(A2, 16);
        WAIT8("1", A3);
        VALIDATE(A3, "1536", "1600", "1664", "1728", "1792", "1856", "1920", "1984");
        CONSUME8(A3, 24);

        // DELAYED OWN-ROWS poison of slot (t-1)&15 (all groups validated).
        if (t >= 1 && lane < 16) {
            unsigned short* pz = hring + ((size_t)((t - 1) & 15) << 16)
                               + (size_t)w * 16384 + (size_t)b * 128;
            asm volatile("global_store_dwordx4 %0, %1, off sc1"
                         :: "v"(pz + lane * 8), "v"(PZ) : "memory");
        }

        // add x-projection partial
        {
            const unsigned d0 = xp.x, d1 = xp.y, d2 = xp.z, d3 = xp.w;
            acc[0][0] += bf2f((unsigned short)(d0 & 0xFFFFu));
            acc[0][1] += bf2f((unsigned short)(d0 >> 16));
            acc[0][2] += bf2f((unsigned short)(d1 & 0xFFFFu));
            acc[0][3] += bf2f((unsigned short)(d1 >> 16));
            acc[1][0] += bf2f((unsigned short)(d2 & 0xFFFFu));
            acc[1][1] += bf2f((unsigned short)(d2 >> 16));
            acc[1][2] += bf2f((unsigned short)(d3 & 0xFFFFu));
            acc[1][3] += bf2f((unsigned short)(d3 >> 16));
        }

        // gate pair-exchange + register-local epilogue
        const bool low = (lr & 8) == 0;
        unsigned short hsv[4];
        #pragma unroll
        for (int r = 0; r < 4; ++r) {
            const float s0 = acc[0][r], s1 = acc[1][r];
            const float x0 = __shfl_xor(s0, 8);
            const float x1 = __shfl_xor(s1, 8);
            const float pi = low ? s0 : x0;
            const float pf = low ? x0 : s0;
            const float po = low ? s1 : x1;
            const float pg = low ? x1 : s1;
            const float ig = 1.f / (1.f + __expf(-pi));
            const float fg = 1.f / (1.f + __expf(-pf));
            const float og = 1.f / (1.f + __expf(-po));
            const float gg = 1.f - 2.f / (__expf(2.f * pg) + 1.f);
            const float cn = fg * cst[r] + ig * gg;
            cst[r] = cn;
            hsv[r] = f2bf(og * (1.f - 2.f / (__expf(2.f * cn) + 1.f)));
        }

        // stage h in LDS (wave-private rows), coalesced stores to slot t+1
        if (low) {
            #pragma unroll
            for (int r = 0; r < 4; ++r)
                L.hs[(w << 4) + (kq << 2) + r][lr] = hsv[r];
        }
        asm volatile("s_waitcnt lgkmcnt(0)" ::: "memory");
        __builtin_amdgcn_sched_barrier(0);
        {
            unsigned short* hout = hring + ((size_t)((t + 1) & 15) << 16);
            if (lane < 16) {
                const int row = (w << 4) + lane;
                const u32v4 hv = *reinterpret_cast<const u32v4*>(&L.hs[row][0]);
                asm volatile("global_store_dwordx4 %0, %1, off sc1"
                             :: "v"(hout + (size_t)row * 1024 + (b << 3)), "v"(hv)
                             : "memory");
            }
        }
        // post own flag WITHOUT draining the h stores (poison net covers it)
        if (lane == 0)
            asm volatile("global_store_dword %0, %1, off sc1"
                         :: "v"(flg + (pw) * 32), "v"(t + 1) : "memory");
    }
}

// ---------------------------------------------------------------------------
__global__ __launch_bounds__(256) void final_gemm(const unsigned short* __restrict__ h_in,
                                                  const unsigned short* __restrict__ WyT,
                                                  float* __restrict__ out) {
    const int tid = threadIdx.x;
    const int w = tid >> 6;
    const int lane = tid & 63;
    const int lr = lane & 15;
    const int kq = lane >> 4;
    const int c0 = blockIdx.x * 16;
    const int k0 = w * 256;

    f32x4 acc[4] = {};
    #pragma unroll 2
    for (int it = 0; it < 8; ++it) {
        const int k = k0 + it * 32 + kq * 8;
        const bfv8 bfr = *reinterpret_cast<const bfv8*>(WyT + (size_t)(c0 + lr) * 1024 + k);
        #pragma unroll
        for (int m = 0; m < 4; ++m) {
            const bfv8 a = *reinterpret_cast<const bfv8*>(h_in + (size_t)(m * 16 + lr) * 1024 + k);
            acc[m] = __builtin_amdgcn_mfma_f32_16x16x32_bf16(a, bfr, acc[m], 0, 0, 0);
        }
    }
    __shared__ float red[4][64][17];
    #pragma unroll
    for (int m = 0; m < 4; ++m)
        #pragma unroll
        for (int r = 0; r < 4; ++r)
            red[w][m * 16 + kq * 4 + r][lr] = acc[m][r];
    __syncthreads();
    #pragma unroll
    for (int u = 0; u < 4; ++u) {
        const int item = u * 256 + tid;
        const int b = item >> 4;
        const int jr = item & 15;
        const float s = red[0][b][jr] + red[1][b][jr] + red[2][b][jr] + red[3][b][jr];
        out[b * 1024 + c0 + jr] = s;
    }
}

// ---------------------------------------------------------------------------
extern "C" void kernel_launch(void* const* d_in, const int* in_sizes, int n_in,
                              void* d_out, int out_size, void* d_ws, size_t ws_size,
                              hipStream_t stream) {
    const float* x = (const float*)d_in[0];
    SrcPtrs sp;
    sp.p[0] = (const float*)d_in[1]; // W_hi
    sp.p[1] = (const float*)d_in[3]; // W_hf
    sp.p[2] = (const float*)d_in[5]; // W_ho
    sp.p[3] = (const float*)d_in[7]; // W_hg
    sp.p[4] = (const float*)d_in[2]; // W_ii
    sp.p[5] = (const float*)d_in[4]; // W_if
    sp.p[6] = (const float*)d_in[6]; // W_io
    sp.p[7] = (const float*)d_in[8]; // W_ig
    sp.p[8] = (const float*)d_in[9]; // W_y

    char* ws = (char*)d_ws;
    unsigned short* Whp   = (unsigned short*)(ws + 0);          //  8 MB
    unsigned short* Wip   = (unsigned short*)(ws + 8388608);    //  8 MB
    unsigned short* Wy    = (unsigned short*)(ws + 16777216);   //  2 MB
    unsigned short* xT    = (unsigned short*)(ws + 18874368);   // 64 MB -> 85983232
    unsigned short* hring = (unsigned short*)(ws + 85983232);   // 16 x 128 KB = 2 MB
    unsigned short* ring  = (unsigned short*)(ws + 88080384);   // xpart, 2 MB
    int*            xflg  = (int*)(ws + 90177536);              // 64 KB
    int*            cflg  = (int*)(ws + 90243072);              // 64 KB
    int*            flg   = (int*)(ws + 90308608);              // 64 KB -> 90374144

    pack_weights<<<dim3(16, 16, 9), 256, 0, stream>>>(sp, Whp, Wip, Wy);
    convert_x<<<32768, 256, 0, stream>>>(x, xT);
    hipMemsetAsync(hring, 0xFF, 16 * 131072, stream);  // poison all slots
    hipMemsetAsync(hring, 0x00, 131072, stream);       // slot 0 = h_{-1} = 0
    hipMemsetAsync(xflg, 0x00, 65536, stream);         // factory progress = 0
    hipMemsetAsync(cflg, 0xFF, 65536, stream);         // consumer xpart progress = -1
    hipMemsetAsync(flg, 0x00, 65536, stream);          // h flags = 0

    lstm_pc<<<256, 256, 0, stream>>>(xT, Whp, Wip, hring, xflg, cflg, flg, ring);

    // h_512 lives in slot 512 & 15 == 0
    final_gemm<<<64, 256, 0, stream>>>(hring, Wy, (float*)d_out);
}

// Round 24
// 3041.799 us; speedup vs baseline: 1.8770x; 1.8770x over previous
//
#include <hip/hip_runtime.h>

// LSTM: B=64, S=512, I=H=O=1024.  bf16 MFMA, fp32 accum.
// R24 = REVERT to R22 (best: 3.047 ms). R23's speculative h-issue proved the
// consumers arrive BEFORE producers store h_t (retries doubled FETCH), so the
// producer-store -> flag -> poll -> load chain is the irreducible critical
// path; pre-issuing cannot hide it. R22 structure:
//  - Per-group poison-validate + interleaved consume (counted vmcnt).
//  - Flags posted WITHOUT store drain; 16-slot poisoned h ring; delayed
//    own-rows re-poison (R18-proven); free-running per-wave chains.
//  - Factories: per-wave, <=4 ahead, cached xT loads, xpart ring + xflg.

typedef __bf16 bfv8 __attribute__((ext_vector_type(8)));
typedef float f32x4 __attribute__((ext_vector_type(4)));
typedef unsigned int u32v4 __attribute__((ext_vector_type(4)));

__device__ __forceinline__ unsigned short f2bf(float x) {
    union { float f; unsigned int u; } v; v.f = x;
    unsigned int r = (v.u + 0x7FFFu + ((v.u >> 16) & 1u)) >> 16;
    return (unsigned short)r;
}
__device__ __forceinline__ float bf2f(unsigned short s) {
    union { unsigned int u; float f; } v; v.u = ((unsigned int)s) << 16;
    return v.f;
}

struct SrcPtrs { const float* p[9]; };

// Device-scope (LLC-coherent) issue — exchange traffic.
#define ISSUE8(A, P, O0, O1, O2, O3, O4, O5, O6, O7)                         \
    asm volatile(                                                            \
        "global_load_dwordx4 %0, %8, off offset:" O0 " sc1\n\t"              \
        "global_load_dwordx4 %1, %8, off offset:" O1 " sc1\n\t"              \
        "global_load_dwordx4 %2, %8, off offset:" O2 " sc1\n\t"              \
        "global_load_dwordx4 %3, %8, off offset:" O3 " sc1\n\t"              \
        "global_load_dwordx4 %4, %8, off offset:" O4 " sc1\n\t"              \
        "global_load_dwordx4 %5, %8, off offset:" O5 " sc1\n\t"              \
        "global_load_dwordx4 %6, %8, off offset:" O6 " sc1\n\t"              \
        "global_load_dwordx4 %7, %8, off offset:" O7 " sc1"                  \
        : "=&v"(A[0]), "=&v"(A[1]), "=&v"(A[2]), "=&v"(A[3]),                \
          "=&v"(A[4]), "=&v"(A[5]), "=&v"(A[6]), "=&v"(A[7])                 \
        : "v"(P)                                                             \
        : "memory")

// Plain cached — factory xT loads (read-only, L2-shared per XCD).
#define ISSUE8C(A, P, O0, O1, O2, O3, O4, O5, O6, O7)                        \
    asm volatile(                                                            \
        "global_load_dwordx4 %0, %8, off offset:" O0 "\n\t"                  \
        "global_load_dwordx4 %1, %8, off offset:" O1 "\n\t"                  \
        "global_load_dwordx4 %2, %8, off offset:" O2 "\n\t"                  \
        "global_load_dwordx4 %3, %8, off offset:" O3 "\n\t"                  \
        "global_load_dwordx4 %4, %8, off offset:" O4 "\n\t"                  \
        "global_load_dwordx4 %5, %8, off offset:" O5 "\n\t"                  \
        "global_load_dwordx4 %6, %8, off offset:" O6 "\n\t"                  \
        "global_load_dwordx4 %7, %8, off offset:" O7                         \
        : "=&v"(A[0]), "=&v"(A[1]), "=&v"(A[2]), "=&v"(A[3]),                \
          "=&v"(A[4]), "=&v"(A[5]), "=&v"(A[6]), "=&v"(A[7])                 \
        : "v"(P)                                                             \
        : "memory")

#define WAIT8(N, A)                                                          \
    do {                                                                     \
        asm volatile("s_waitcnt vmcnt(" N ")"                                \
                     : "+v"(A[0]), "+v"(A[1]), "+v"(A[2]), "+v"(A[3]),       \
                       "+v"(A[4]), "+v"(A[5]), "+v"(A[6]), "+v"(A[7])        \
                     :: "memory");                                           \
        __builtin_amdgcn_sched_barrier(0);                                   \
    } while (0)

// 8 k-steps x 2 N-tiles vs fragment-linear LDS panel: lane-stride-1.
#define CONSUME8(A, IT0)                                                     \
    _Pragma("unroll")                                                        \
    for (int j = 0; j < 8; ++j) {                                            \
        _Pragma("unroll")                                                    \
        for (int n = 0; n < 2; ++n) {                                        \
            const int off = (((((IT0) + j) << 1) | n) << 10) + (lane << 4);  \
            acc[n] = __builtin_amdgcn_mfma_f32_16x16x32_bf16(                \
                A[j], *(const bfv8*)(Lw + off), acc[n], 0, 0, 0);            \
        }                                                                    \
    }

#define CHKMAX(A)                                                            \
    _Pragma("unroll")                                                        \
    for (int j = 0; j < 8; ++j) {                                            \
        const u32v4 u = __builtin_bit_cast(u32v4, A[j]);                     \
        mh = mh > u.x ? mh : u.x;                                            \
        mh = mh > u.y ? mh : u.y;                                            \
        mh = mh > u.z ? mh : u.z;                                            \
        mh = mh > u.w ? mh : u.w;                                            \
    }

// Per-group validate: check A for poison; rare retry re-issues and drains.
#define VALIDATE(A, O0, O1, O2, O3, O4, O5, O6, O7)                          \
    do {                                                                     \
        unsigned mh = 0;                                                     \
        CHKMAX(A)                                                            \
        int guard = 0;                                                       \
        while (__any(mh == 0xFFFFFFFFu) && ++guard <= 65536) {               \
            ISSUE8(A, hp, O0, O1, O2, O3, O4, O5, O6, O7);                   \
            WAIT8("0", A);                                                   \
            mh = 0;                                                          \
            CHKMAX(A)                                                        \
        }                                                                    \
    } while (0)

// ---------------------------------------------------------------------------
__global__ __launch_bounds__(256) void pack_weights(SrcPtrs sp,
                                                    unsigned short* __restrict__ Whp,
                                                    unsigned short* __restrict__ Wip,
                                                    unsigned short* __restrict__ Wy) {
    __shared__ float tile[64][65];
    const int z = blockIdx.z;
    const float* __restrict__ src = sp.p[z];
    const int n0 = blockIdx.x * 64, k0 = blockIdx.y * 64;
    const int tc = threadIdx.x & 63, tq = threadIdx.x >> 6;

    #pragma unroll
    for (int r = 0; r < 16; ++r) {
        const int kk = tq * 16 + r;
        tile[kk][tc] = src[(size_t)(k0 + kk) * 1024 + n0 + tc];
    }
    __syncthreads();
    #pragma unroll
    for (int r = 0; r < 16; ++r) {
        const int nl = tq * 16 + r;
        const int n = n0 + nl;
        const int k = k0 + tc;
        const unsigned short v = f2bf(tile[tc][nl]);
        if (z < 8) {
            const int g = z & 3;
            const int blk = n >> 3;
            const int c = (g << 3) | (n & 7);
            const int lanef = (c & 15) | (((k >> 3) & 3) << 4);
            const size_t off = ((size_t)((((blk << 5) | (k >> 5)) << 1) | (c >> 4)) << 9)
                             + (lanef << 3) + (k & 7);
            (z < 4 ? Whp : Wip)[off] = v;
        } else {
            Wy[(size_t)n * 1024 + k] = v;
        }
    }
}

// ---------------------------------------------------------------------------
__global__ __launch_bounds__(256) void convert_x(const float* __restrict__ x,
                                                 unsigned short* __restrict__ xT) {
    const size_t gid = (size_t)blockIdx.x * 256 + threadIdx.x;
    const int i0 = (int)(gid & 255) * 4;
    const size_t row = gid >> 8;            // dst row = t*64 + b
    const int t = (int)(row >> 6), b = (int)(row & 63);
    const float4 v = *reinterpret_cast<const float4*>(x + (((size_t)b * 512 + t) << 10) + i0);
    ushort4 o;
    o.x = f2bf(v.x); o.y = f2bf(v.y); o.z = f2bf(v.z); o.w = f2bf(v.w);
    *reinterpret_cast<ushort4*>(xT + (row << 10) + i0) = o;
}

// ---------------------------------------------------------------------------
// R24 unified producer/consumer kernel (R22 structure). 256 blocks x 256 thr.
// ---------------------------------------------------------------------------
__global__ __launch_bounds__(256) void lstm_pc(const unsigned short* __restrict__ xT,
                                               const unsigned short* __restrict__ Whp,
                                               const unsigned short* __restrict__ Wip,
                                               unsigned short* __restrict__ hring,
                                               int* __restrict__ xflg,
                                               int* __restrict__ cflg,
                                               int* __restrict__ flg,
                                               unsigned short* __restrict__ ring) {
    __shared__ struct {
        __align__(16) unsigned char wp[65536];   // fragment-linear W panel
        __align__(16) unsigned char pad[32768];  // force 1 block/CU
        __align__(16) unsigned short hs[64][8];  // h store-coalescing tile
    } L;
    unsigned char* Lw = L.wp;

    const int tid = threadIdx.x;
    const int w = tid >> 6;           // 0..3
    const int lane = tid & 63;
    const int lr = lane & 15;
    const int kq = lane >> 4;
    const bool isFactory = (blockIdx.x >= 128);
    const int b = isFactory ? (blockIdx.x - 128) : blockIdx.x;   // pair id

    // ---- stage panel (W_h for consumers, W_i for factories) ----
    {
        const unsigned short* src = (isFactory ? Wip : Whp) + ((size_t)b << 15);
        #pragma unroll
        for (int s = 0; s < 16; ++s) {
            const int c = s * 256 + tid;          // 16B chunk 0..4095
            *(bfv8*)(L.wp + c * 16) = *(const bfv8*)(src + c * 8);
        }
    }
    __syncthreads();   // only block-wide barrier

    const int roff = ((w << 4) + lr) * 1024 + kq * 8;
    const int pw = (b << 2) + w;                      // pair-wave id 0..511

    if (isFactory) {
        // ===== x-factory: per-wave, <=4 ahead, CACHED xT loads =====
        for (int tt = 0; tt < 512; ++tt) {
            const int* cfp = cflg + pw * 32;
            while (__hip_atomic_load(cfp, __ATOMIC_RELAXED, __HIP_MEMORY_SCOPE_AGENT) < tt - 4)
                __builtin_amdgcn_s_sleep(2);

            const unsigned short* Axp = xT + ((size_t)tt << 16) + roff;
            f32x4 acc[2] = {};
            bfv8 A0[8], A1[8];
            ISSUE8C(A0, Axp, "0", "64", "128", "192", "256", "320", "384", "448");
            ISSUE8C(A1, Axp, "512", "576", "640", "704", "768", "832", "896", "960");
            WAIT8("8", A0);
            CONSUME8(A0, 0);
            ISSUE8C(A0, Axp, "1024", "1088", "1152", "1216", "1280", "1344", "1408", "1472");
            WAIT8("8", A1);
            CONSUME8(A1, 8);
            ISSUE8C(A1, Axp, "1536", "1600", "1664", "1728", "1792", "1856", "1920", "1984");
            WAIT8("8", A0);
            CONSUME8(A0, 16);
            WAIT8("0", A1);
            CONSUME8(A1, 24);

            unsigned short vv[8];
            #pragma unroll
            for (int n = 0; n < 2; ++n)
                #pragma unroll
                for (int r = 0; r < 4; ++r)
                    vv[n * 4 + r] = f2bf(acc[n][r]);
            unsigned short* rp = ring + (((size_t)(b << 2) + (tt & 3)) * 4 + w) * 512 + lane * 8;
            asm volatile("global_store_dwordx4 %0, %1, off sc1"
                         :: "v"(rp), "v"(*(const u32v4*)vv) : "memory");
            asm volatile("s_waitcnt vmcnt(0)" ::: "memory");   // xpart has no poison net
            if (lane == 0)
                asm volatile("global_store_dword %0, %1, off sc1"
                             :: "v"(xflg + pw * 32), "v"(tt + 1) : "memory");
        }
        return;
    }

    // ================= consumer: free-running per-wave chain =================
    float cst[4] = {0.f, 0.f, 0.f, 0.f};
    bfv8 A0[8], A1[8], A2[8], A3[8];
    const u32v4 PZ = {0xFFFFFFFFu, 0xFFFFFFFFu, 0xFFFFFFFFu, 0xFFFFFFFFu};

    for (int t = 0; t < 512; ++t) {
        const unsigned short* hp = hring + ((size_t)(t & 15) << 16) + roff;

        // xpart: poll partner factory wave's flag, then load own 16B chunk
        const int* xfp = xflg + pw * 32;
        while (__hip_atomic_load(xfp, __ATOMIC_RELAXED, __HIP_MEMORY_SCOPE_AGENT) < t + 1)
            __builtin_amdgcn_s_sleep(1);
        u32v4 xp;
        const unsigned short* rp = ring + (((size_t)(b << 2) + (t & 3)) * 4 + w) * 512 + lane * 8;
        asm volatile("global_load_dwordx4 %0, %1, off sc1"
                     : "=v"(xp) : "v"(rp) : "memory");

        // h availability: poll 32 same-wave producer flags per K-group, then
        // issue that group's loads (pipelined: polls overlap earlier flights)
        #define POLLG(G)                                                      \
            if (t > 0) {                                                      \
                const int* fp = flg + (((((G) << 5) + (lane & 31)) << 2) | w) * 32; \
                for (;;) {                                                    \
                    const int f = __hip_atomic_load(fp, __ATOMIC_RELAXED,     \
                                                    __HIP_MEMORY_SCOPE_AGENT);\
                    if (__all(f >= t)) break;                                 \
                    __builtin_amdgcn_s_sleep(1);                              \
                }                                                             \
            }
        POLLG(0) ISSUE8(A0, hp, "0", "64", "128", "192", "256", "320", "384", "448");
        POLLG(1) ISSUE8(A1, hp, "512", "576", "640", "704", "768", "832", "896", "960");
        POLLG(2) ISSUE8(A2, hp, "1024", "1088", "1152", "1216", "1280", "1344", "1408", "1472");
        POLLG(3) ISSUE8(A3, hp, "1536", "1600", "1664", "1728", "1792", "1856", "1920", "1984");
        #undef POLLG

        // per-group validate + interleaved consume (counted vmcnt):
        // outstanding at this point: <=3 prior stores + xp + 32 loads.
        f32x4 acc[2] = {};
        WAIT8("24", A0);                    // stores drained, xp + A0 complete
        asm volatile("" : "+v"(xp));        // xp secured in regs
        VALIDATE(A0, "0", "64", "128", "192", "256", "320", "384", "448");
        CONSUME8(A0, 0);
        // release the xpart slot for the factory (xp secured above)
        if (lane == 0)
            asm volatile("global_store_dword %0, %1, off sc1"
                         :: "v"(cflg + pw * 32), "v"(t) : "memory");
        WAIT8("17", A1);                    // A1 complete (cflg store +1)
        VALIDATE(A1, "512", "576", "640", "704", "768", "832", "896", "960");
        CONSUME8(A1, 8);
        WAIT8("9", A2);                     // A2 complete
        VALIDATE(A2, "1024", "1088", "1152", "1216", "1280", "1344", "1408", "1472");
        CONSUME8(A2, 16);
        WAIT8("1", A3);                     // A3 complete
        VALIDATE(A3, "1536", "1600", "1664", "1728", "1792", "1856", "1920", "1984");
        CONSUME8(A3, 24);

        // DELAYED OWN-ROWS poison of slot (t-1)&15 (all groups validated).
        if (t >= 1 && lane < 16) {
            unsigned short* pz = hring + ((size_t)((t - 1) & 15) << 16)
                               + (size_t)w * 16384 + (size_t)b * 128;
            asm volatile("global_store_dwordx4 %0, %1, off sc1"
                         :: "v"(pz + lane * 8), "v"(PZ) : "memory");
        }

        // add x-projection partial
        {
            const unsigned d0 = xp.x, d1 = xp.y, d2 = xp.z, d3 = xp.w;
            acc[0][0] += bf2f((unsigned short)(d0 & 0xFFFFu));
            acc[0][1] += bf2f((unsigned short)(d0 >> 16));
            acc[0][2] += bf2f((unsigned short)(d1 & 0xFFFFu));
            acc[0][3] += bf2f((unsigned short)(d1 >> 16));
            acc[1][0] += bf2f((unsigned short)(d2 & 0xFFFFu));
            acc[1][1] += bf2f((unsigned short)(d2 >> 16));
            acc[1][2] += bf2f((unsigned short)(d3 & 0xFFFFu));
            acc[1][3] += bf2f((unsigned short)(d3 >> 16));
        }

        // gate pair-exchange + register-local epilogue
        const bool low = (lr & 8) == 0;
        unsigned short hsv[4];
        #pragma unroll
        for (int r = 0; r < 4; ++r) {
            const float s0 = acc[0][r], s1 = acc[1][r];
            const float x0 = __shfl_xor(s0, 8);
            const float x1 = __shfl_xor(s1, 8);
            const float pi = low ? s0 : x0;
            const float pf = low ? x0 : s0;
            const float po = low ? s1 : x1;
            const float pg = low ? x1 : s1;
            const float ig = 1.f / (1.f + __expf(-pi));
            const float fg = 1.f / (1.f + __expf(-pf));
            const float og = 1.f / (1.f + __expf(-po));
            const float gg = 1.f - 2.f / (__expf(2.f * pg) + 1.f);
            const float cn = fg * cst[r] + ig * gg;
            cst[r] = cn;
            hsv[r] = f2bf(og * (1.f - 2.f / (__expf(2.f * cn) + 1.f)));
        }

        // stage h in LDS (wave-private rows), coalesced stores to slot t+1
        if (low) {
            #pragma unroll
            for (int r = 0; r < 4; ++r)
                L.hs[(w << 4) + (kq << 2) + r][lr] = hsv[r];
        }
        asm volatile("s_waitcnt lgkmcnt(0)" ::: "memory");
        __builtin_amdgcn_sched_barrier(0);
        {
            unsigned short* hout = hring + ((size_t)((t + 1) & 15) << 16);
            if (lane < 16) {
                const int row = (w << 4) + lane;
                const u32v4 hv = *reinterpret_cast<const u32v4*>(&L.hs[row][0]);
                asm volatile("global_store_dwordx4 %0, %1, off sc1"
                             :: "v"(hout + (size_t)row * 1024 + (b << 3)), "v"(hv)
                             : "memory");
            }
        }
        // post own flag WITHOUT draining the h stores (poison net covers it)
        if (lane == 0)
            asm volatile("global_store_dword %0, %1, off sc1"
                         :: "v"(flg + (pw) * 32), "v"(t + 1) : "memory");
    }
}

// ---------------------------------------------------------------------------
__global__ __launch_bounds__(256) void final_gemm(const unsigned short* __restrict__ h_in,
                                                  const unsigned short* __restrict__ WyT,
                                                  float* __restrict__ out) {
    const int tid = threadIdx.x;
    const int w = tid >> 6;
    const int lane = tid & 63;
    const int lr = lane & 15;
    const int kq = lane >> 4;
    const int c0 = blockIdx.x * 16;
    const int k0 = w * 256;

    f32x4 acc[4] = {};
    #pragma unroll 2
    for (int it = 0; it < 8; ++it) {
        const int k = k0 + it * 32 + kq * 8;
        const bfv8 bfr = *reinterpret_cast<const bfv8*>(WyT + (size_t)(c0 + lr) * 1024 + k);
        #pragma unroll
        for (int m = 0; m < 4; ++m) {
            const bfv8 a = *reinterpret_cast<const bfv8*>(h_in + (size_t)(m * 16 + lr) * 1024 + k);
            acc[m] = __builtin_amdgcn_mfma_f32_16x16x32_bf16(a, bfr, acc[m], 0, 0, 0);
        }
    }
    __shared__ float red[4][64][17];
    #pragma unroll
    for (int m = 0; m < 4; ++m)
        #pragma unroll
        for (int r = 0; r < 4; ++r)
            red[w][m * 16 + kq * 4 + r][lr] = acc[m][r];
    __syncthreads();
    #pragma unroll
    for (int u = 0; u < 4; ++u) {
        const int item = u * 256 + tid;
        const int b = item >> 4;
        const int jr = item & 15;
        const float s = red[0][b][jr] + red[1][b][jr] + red[2][b][jr] + red[3][b][jr];
        out[b * 1024 + c0 + jr] = s;
    }
}

// ---------------------------------------------------------------------------
extern "C" void kernel_launch(void* const* d_in, const int* in_sizes, int n_in,
                              void* d_out, int out_size, void* d_ws, size_t ws_size,
                              hipStream_t stream) {
    const float* x = (const float*)d_in[0];
    SrcPtrs sp;
    sp.p[0] = (const float*)d_in[1]; // W_hi
    sp.p[1] = (const float*)d_in[3]; // W_hf
    sp.p[2] = (const float*)d_in[5]; // W_ho
    sp.p[3] = (const float*)d_in[7]; // W_hg
    sp.p[4] = (const float*)d_in[2]; // W_ii
    sp.p[5] = (const float*)d_in[4]; // W_if
    sp.p[6] = (const float*)d_in[6]; // W_io
    sp.p[7] = (const float*)d_in[8]; // W_ig
    sp.p[8] = (const float*)d_in[9]; // W_y

    char* ws = (char*)d_ws;
    unsigned short* Whp   = (unsigned short*)(ws + 0);          //  8 MB
    unsigned short* Wip   = (unsigned short*)(ws + 8388608);    //  8 MB
    unsigned short* Wy    = (unsigned short*)(ws + 16777216);   //  2 MB
    unsigned short* xT    = (unsigned short*)(ws + 18874368);   // 64 MB -> 85983232
    unsigned short* hring = (unsigned short*)(ws + 85983232);   // 16 x 128 KB = 2 MB
    unsigned short* ring  = (unsigned short*)(ws + 88080384);   // xpart, 2 MB
    int*            xflg  = (int*)(ws + 90177536);              // 64 KB
    int*            cflg  = (int*)(ws + 90243072);              // 64 KB
    int*            flg   = (int*)(ws + 90308608);              // 64 KB -> 90374144

    pack_weights<<<dim3(16, 16, 9), 256, 0, stream>>>(sp, Whp, Wip, Wy);
    convert_x<<<32768, 256, 0, stream>>>(x, xT);
    hipMemsetAsync(hring, 0xFF, 16 * 131072, stream);  // poison all slots
    hipMemsetAsync(hring, 0x00, 131072, stream);       // slot 0 = h_{-1} = 0
    hipMemsetAsync(xflg, 0x00, 65536, stream);         // factory progress = 0
    hipMemsetAsync(cflg, 0xFF, 65536, stream);         // consumer xpart progress = -1
    hipMemsetAsync(flg, 0x00, 65536, stream);          // h flags = 0

    lstm_pc<<<256, 256, 0, stream>>>(xT, Whp, Wip, hring, xflg, cflg, flg, ring);

    // h_512 lives in slot 512 & 15 == 0
    final_gemm<<<64, 256, 0, stream>>>(hring, Wy, (float*)d_out);
}